// Round 17
// baseline (1218.266 us; speedup 1.0000x reference)
//
#include <hip/hip_runtime.h>
#include <hip/hip_bf16.h>

typedef __bf16 bf16;
typedef __bf16 bf16x8 __attribute__((ext_vector_type(8)));
typedef __bf16 bf16x4 __attribute__((ext_vector_type(4)));
typedef __bf16 bf16x2 __attribute__((ext_vector_type(2)));
typedef float f32x4 __attribute__((ext_vector_type(4)));
typedef float f32x16 __attribute__((ext_vector_type(16)));
typedef unsigned int u32x4 __attribute__((ext_vector_type(4)));

#define MFMA_BF16(a, b, c) __builtin_amdgcn_mfma_f32_16x16x32_bf16((a), (b), (c), 0, 0, 0)
#define MFMA32(a, b, c) __builtin_amdgcn_mfma_f32_32x32x16_bf16((a), (b), (c), 0, 0, 0)

#if defined(__has_builtin)
#if __has_builtin(__builtin_amdgcn_exp2f)
#define EXP2F(x) __builtin_amdgcn_exp2f(x)
#endif
#endif
#ifndef EXP2F
#define EXP2F(x) exp2f(x)
#endif

// Problem constants
static constexpr int Bc = 4, Lc = 2048, Dc = 1024, Hc = 16, DKc = 64;
static constexpr int BLc = Bc * Lc;  // 8192
// exp(s/8) == exp2(s * log2(e)/8)
static constexpr float CEXP = 0.18033688011112042f;

__device__ inline unsigned pk2(float a, float b) {
  bf16x2 t;
  t[0] = (bf16)a;
  t[1] = (bf16)b;
  return __builtin_bit_cast(unsigned, t);
}

// ---------------- all four weight matrices f32 -> bf16, one launch ----------
__global__ __launch_bounds__(256) void cvt_all(const float* __restrict__ s0,
                                               const float* __restrict__ s1,
                                               const float* __restrict__ s2,
                                               const float* __restrict__ s3,
                                               bf16* __restrict__ dst) {
  size_t i = ((size_t)blockIdx.x * 256 + threadIdx.x) * 8;
  const float* srcs[4] = {s0, s1, s2, s3};
  const float* sp = srcs[i >> 20] + (i & 1048575);
  float4 f0 = ((const float4*)sp)[0];
  float4 f1 = ((const float4*)sp)[1];
  bf16x8 o;
  o[0] = (bf16)f0.x; o[1] = (bf16)f0.y; o[2] = (bf16)f0.z; o[3] = (bf16)f0.w;
  o[4] = (bf16)f1.x; o[5] = (bf16)f1.y; o[6] = (bf16)f1.z; o[7] = (bf16)f1.w;
  *(bf16x8*)(dst + i) = o;
}

// ---------------- merged QKV projection (unchanged from R10) -----------------
__global__ __launch_bounds__(256) void qkv_gemm(const float* __restrict__ qin,
                                                const float* __restrict__ kin,
                                                const float* __restrict__ vin,
                                                const bf16* __restrict__ Wb,
                                                bf16* __restrict__ qh,
                                                bf16* __restrict__ kh,
                                                bf16* __restrict__ vt) {
  __shared__ bf16 As[128][72];
  __shared__ bf16 Bs[128][72];
  const int t = threadIdx.x;
  const int lane = t & 63, wid = t >> 6;
  const int wr = wid >> 1, wc = wid & 1;
  const int which = blockIdx.y >> 3;
  const int m0 = blockIdx.x * 128, n0 = (blockIdx.y & 7) * 128;
  const float* A = which == 0 ? qin : which == 1 ? kin : vin;
  const bf16* Bw = Wb + ((size_t)which << 20);
  const int sub = t & 7, srow = t >> 3;

  f32x4 acc[4][4] = {};

  for (int kt = 0; kt < 1024; kt += 64) {
#pragma unroll
    for (int s = 0; s < 4; ++s) {
      int r = srow + 32 * s;
      const float4* pa = (const float4*)(A + (size_t)(m0 + r) * 1024 + kt + sub * 8);
      float4 f0 = pa[0], f1 = pa[1];
      bf16x8 o;
      o[0] = (bf16)f0.x; o[1] = (bf16)f0.y; o[2] = (bf16)f0.z; o[3] = (bf16)f0.w;
      o[4] = (bf16)f1.x; o[5] = (bf16)f1.y; o[6] = (bf16)f1.z; o[7] = (bf16)f1.w;
      *(bf16x8*)&As[r][sub * 8] = o;
    }
#pragma unroll
    for (int s = 0; s < 4; ++s) {
      int r = srow + 32 * s;
      u32x4 u = *(const u32x4*)(Bw + (size_t)(n0 + r) * 1024 + kt + sub * 8);
      *(u32x4*)&Bs[r][sub * 8] = u;
    }
    __syncthreads();
#pragma unroll
    for (int c = 0; c < 2; ++c) {
      const int ko = c * 32 + (lane >> 4) * 8;
      bf16x8 af[4], bfr[4];
#pragma unroll
      for (int m = 0; m < 4; ++m)
        af[m] = *(const bf16x8*)&As[wr * 64 + m * 16 + (lane & 15)][ko];
#pragma unroll
      for (int n = 0; n < 4; ++n)
        bfr[n] = *(const bf16x8*)&Bs[wc * 64 + n * 16 + (lane & 15)][ko];
#pragma unroll
      for (int m = 0; m < 4; ++m)
#pragma unroll
        for (int n = 0; n < 4; ++n)
          acc[m][n] = MFMA_BF16(af[m], bfr[n], acc[m][n]);
    }
    __syncthreads();
  }

  const int rbase = m0 + wr * 64 + (lane >> 4) * 4;
  const int cbase = n0 + wc * 64 + (lane & 15);
  if (which < 2) {
    bf16* C = which == 0 ? qh : kh;
#pragma unroll
    for (int m = 0; m < 4; ++m)
#pragma unroll
      for (int n = 0; n < 4; ++n)
#pragma unroll
        for (int r = 0; r < 4; ++r) {
          size_t row = (size_t)(rbase + m * 16 + r);
          size_t col = (size_t)(cbase + n * 16);
          C[row * 1024 + col] = (bf16)acc[m][n][r];
        }
  } else {
#pragma unroll
    for (int m = 0; m < 4; ++m)
#pragma unroll
      for (int n = 0; n < 4; ++n) {
        int row = rbase + m * 16;
        int col = cbase + n * 16;
        bf16x4 o;
#pragma unroll
        for (int r = 0; r < 4; ++r) o[r] = (bf16)acc[m][n][r];
        size_t dst = ((size_t)((row >> 11) << 10) + col) * 2048 + (row & 2047);
        *(bf16x4*)(vt + dst) = o;
      }
  }
}

// ---------------- fc GEMM (unchanged from R10) ----------------
__global__ __launch_bounds__(256) void fc_gemm(const bf16* __restrict__ A,
                                               const bf16* __restrict__ Bw,
                                               float* __restrict__ C,
                                               const float* __restrict__ resid) {
  __shared__ bf16 As[128][72];
  __shared__ bf16 Bs[128][72];
  const int t = threadIdx.x;
  const int lane = t & 63, wid = t >> 6;
  const int wr = wid >> 1, wc = wid & 1;
  const int m0 = blockIdx.x * 128, n0 = blockIdx.y * 128;
  const int sub = t & 7, srow = t >> 3;

  f32x4 acc[4][4] = {};

  for (int kt = 0; kt < 1024; kt += 64) {
#pragma unroll
    for (int s = 0; s < 4; ++s) {
      int r = srow + 32 * s;
      u32x4 u = *(const u32x4*)(A + (size_t)(m0 + r) * 1024 + kt + sub * 8);
      *(u32x4*)&As[r][sub * 8] = u;
    }
#pragma unroll
    for (int s = 0; s < 4; ++s) {
      int r = srow + 32 * s;
      u32x4 u = *(const u32x4*)(Bw + (size_t)(n0 + r) * 1024 + kt + sub * 8);
      *(u32x4*)&Bs[r][sub * 8] = u;
    }
    __syncthreads();
#pragma unroll
    for (int c = 0; c < 2; ++c) {
      const int ko = c * 32 + (lane >> 4) * 8;
      bf16x8 af[4], bfr[4];
#pragma unroll
      for (int m = 0; m < 4; ++m)
        af[m] = *(const bf16x8*)&As[wr * 64 + m * 16 + (lane & 15)][ko];
#pragma unroll
      for (int n = 0; n < 4; ++n)
        bfr[n] = *(const bf16x8*)&Bs[wc * 64 + n * 16 + (lane & 15)][ko];
#pragma unroll
      for (int m = 0; m < 4; ++m)
#pragma unroll
        for (int n = 0; n < 4; ++n)
          acc[m][n] = MFMA_BF16(af[m], bfr[n], acc[m][n]);
    }
    __syncthreads();
  }

  const int rbase = m0 + wr * 64 + (lane >> 4) * 4;
  const int cbase = n0 + wc * 64 + (lane & 15);
#pragma unroll
  for (int m = 0; m < 4; ++m)
#pragma unroll
    for (int n = 0; n < 4; ++n)
#pragma unroll
      for (int r = 0; r < 4; ++r) {
        size_t row = (size_t)(rbase + m * 16 + r);
        size_t col = (size_t)(cbase + n * 16);
        C[row * 1024 + col] = acc[m][n][r] + resid[row * 1024 + col];
      }
}

// ---------------- fused attention (R14 champion body) ----------------
// Single change vs R14: phase-B stores are NON-TEMPORAL (clang ext-vector
// f32x4, since __builtin_nontemporal_store rejects HIP_vector_type). The
// 1.07 GB attn matrix is write-once/read-never; nt keeps K panels (re-read
// 16x per (b,h)) and neighbors' operands L2-resident.
__global__ __launch_bounds__(256, 4) void attn_kernel(const bf16* __restrict__ qh,
                                                      const bf16* __restrict__ kh,
                                                      const bf16* __restrict__ vt,
                                                      bf16* __restrict__ ctx,
                                                      float* __restrict__ attn_out) {
  __shared__ bf16 Ks[64][72];
  __shared__ bf16 Vs[64][72];  // phase A: V[dv][token]; phase B: K rows 64-127
  const int t = threadIdx.x, lane = t & 63, w = t >> 6;
  const int hi = lane >> 5, ql = lane & 31;
  const int qt = blockIdx.x, h = blockIdx.y, b = blockIdx.z;
  const size_t rowbase = (size_t)b * 2048;
  const int qrow = qt * 128 + w * 32 + ql;
  const bf16* kbase = kh + rowbase * 1024 + h * 64;
  const bf16* vbase = vt + (size_t)(b * 16 + h) * 64 * 2048;
  const int sub = t & 7, srow = t >> 3;

  bf16x8 qf[4];
  {
    const bf16* qp = qh + (rowbase + qrow) * 1024 + h * 64 + hi * 8;
#pragma unroll
    for (int c = 0; c < 4; ++c) qf[c] = *(const bf16x8*)(qp + c * 16);
  }

  f32x16 cacc[2] = {};
  float zacc = 0.f;

  // ---------- Phase A (single-buffered, as R14) ----------
  for (int kt = 0; kt < 2048; kt += 64) {
    __syncthreads();
#pragma unroll
    for (int s = 0; s < 2; ++s) {
      int r = srow + 32 * s;
      *(u32x4*)&Ks[r][sub * 8] =
          *(const u32x4*)(kbase + (size_t)(kt + r) * 1024 + sub * 8);
      *(u32x4*)&Vs[r][sub * 8] =
          *(const u32x4*)(vbase + (size_t)r * 2048 + kt + sub * 8);
    }
    __syncthreads();
#pragma unroll
    for (int sb = 0; sb < 2; ++sb) {
      f32x16 s = {};
#pragma unroll
      for (int c = 0; c < 4; ++c) {
        bf16x8 kf = *(const bf16x8*)&Ks[sb * 32 + ql][c * 16 + hi * 8];
        s = MFMA32(kf, qf[c], s);
      }
      unsigned pv[4][2];
#pragma unroll
      for (int o = 0; o < 4; ++o)
#pragma unroll
        for (int d = 0; d < 2; ++d) {
          float e0 = EXP2F(s[o * 4 + 2 * d] * CEXP);
          float e1 = EXP2F(s[o * 4 + 2 * d + 1] * CEXP);
          zacc += e0 + e1;
          pv[o][d] = pk2(e0, e1);
        }
      bf16x8 pa[2];
#pragma unroll
      for (int c = 0; c < 2; ++c) {
        u32x4 pu;
#pragma unroll
        for (int d = 0; d < 2; ++d) {
          unsigned a = pv[2 * c][d], bq = pv[2 * c + 1][d];
          unsigned as = (unsigned)__shfl_xor((int)a, 32);
          unsigned bs = (unsigned)__shfl_xor((int)bq, 32);
          pu[d] = hi ? bs : a;
          pu[2 + d] = hi ? bq : as;
        }
        pa[c] = __builtin_bit_cast(bf16x8, pu);
      }
#pragma unroll
      for (int n = 0; n < 2; ++n)
#pragma unroll
        for (int c = 0; c < 2; ++c) {
          bf16x8 vf = *(const bf16x8*)&Vs[n * 32 + ql][sb * 32 + c * 16 + hi * 8];
          cacc[n] = MFMA32(pa[c], vf, cacc[n]);
        }
    }
  }

  float z = zacc + __shfl_xor(zacc, 32);
  float rz = 1.0f / z;

  // ctx write: per-element shfl (no rzv array)
#pragma unroll
  for (int g = 0; g < 16; ++g) {
    int crow = (g & 3) + 8 * (g >> 2) + 4 * hi;
    float rv = __shfl(rz, crow);
    size_t row = rowbase + (size_t)(qt * 128 + w * 32 + crow);
    ctx[row * 1024 + h * 64 + ql] = (bf16)(cacc[0][g] * rv);
    ctx[row * 1024 + h * 64 + 32 + ql] = (bf16)(cacc[1][g] * rv);
  }

  // ---------- Phase B: attn = exp(s)/Z, 128 K-rows per barrier pair ----------
  float* abase = attn_out + ((size_t)(b * 16 + h) * 2048 + qrow) * 2048;
  for (int kt = 0; kt < 2048; kt += 128) {
    __syncthreads();  // previous 128-row chunk fully consumed
#pragma unroll
    for (int s = 0; s < 2; ++s) {
      int r = srow + 32 * s;
      *(u32x4*)&Ks[r][sub * 8] =
          *(const u32x4*)(kbase + (size_t)(kt + r) * 1024 + sub * 8);
      *(u32x4*)&Vs[r][sub * 8] =
          *(const u32x4*)(kbase + (size_t)(kt + 64 + r) * 1024 + sub * 8);
    }
    __syncthreads();
#pragma unroll
    for (int half = 0; half < 2; ++half) {
      const bf16(*Kb)[72] = half ? Vs : Ks;
      const int koff = kt + half * 64;
#pragma unroll
      for (int sb = 0; sb < 2; ++sb) {
        f32x16 s = {};
#pragma unroll
        for (int c = 0; c < 4; ++c) {
          bf16x8 kf = *(const bf16x8*)&Kb[sb * 32 + ql][c * 16 + hi * 8];
          s = MFMA32(kf, qf[c], s);
        }
#pragma unroll
        for (int o = 0; o < 4; ++o) {
          f32x4 v4;
          v4[0] = EXP2F(s[o * 4 + 0] * CEXP) * rz;
          v4[1] = EXP2F(s[o * 4 + 1] * CEXP) * rz;
          v4[2] = EXP2F(s[o * 4 + 2] * CEXP) * rz;
          v4[3] = EXP2F(s[o * 4 + 3] * CEXP) * rz;
          __builtin_nontemporal_store(
              v4, (f32x4*)(abase + koff + sb * 32 + o * 8 + hi * 4));
        }
      }
    }
  }
}

// ---------------- LayerNorm (in-place on d_out rows) ----------------
__global__ __launch_bounds__(256) void ln_kernel(float* __restrict__ io,
                                                 const float* __restrict__ g,
                                                 const float* __restrict__ bta) {
  const int row = blockIdx.x, t = threadIdx.x;
  float4* rp = (float4*)(io + (size_t)row * 1024);
  float4 v = rp[t];
  float s = v.x + v.y + v.z + v.w;
  float s2 = v.x * v.x + v.y * v.y + v.z * v.z + v.w * v.w;
#pragma unroll
  for (int off = 32; off >= 1; off >>= 1) {
    s += __shfl_xor(s, off);
    s2 += __shfl_xor(s2, off);
  }
  __shared__ float ls[4], ls2[4];
  const int w = t >> 6;
  if ((t & 63) == 0) { ls[w] = s; ls2[w] = s2; }
  __syncthreads();
  s = ls[0] + ls[1] + ls[2] + ls[3];
  s2 = ls2[0] + ls2[1] + ls2[2] + ls2[3];
  float mu = s * (1.f / 1024.f);
  float var = s2 * (1.f / 1024.f) - mu * mu;
  float rs = rsqrtf(var + 1e-6f);
  float4 gv = ((const float4*)g)[t];
  float4 bv = ((const float4*)bta)[t];
  v.x = (v.x - mu) * rs * gv.x + bv.x;
  v.y = (v.y - mu) * rs * gv.y + bv.y;
  v.z = (v.z - mu) * rs * gv.z + bv.z;
  v.w = (v.w - mu) * rs * gv.w + bv.w;
  rp[t] = v;
}

extern "C" void kernel_launch(void* const* d_in, const int* in_sizes, int n_in,
                              void* d_out, int out_size, void* d_ws, size_t ws_size,
                              hipStream_t stream) {
  (void)in_sizes; (void)n_in; (void)out_size; (void)ws_size;
  const float* q    = (const float*)d_in[0];
  const float* k    = (const float*)d_in[1];
  const float* v    = (const float*)d_in[2];
  const float* Wq   = (const float*)d_in[3];
  const float* Wk   = (const float*)d_in[4];
  const float* Wv   = (const float*)d_in[5];
  const float* Wfc  = (const float*)d_in[6];
  const float* ln_g = (const float*)d_in[7];
  const float* ln_b = (const float*)d_in[8];

  char* ws = (char*)d_ws;
  const size_t MB = 1024ull * 1024ull;
  bf16* wall = (bf16*)(ws + 0 * MB);   // wq|wk|wv|wfc contiguous, 2 MB each
  bf16* wfcb = (bf16*)(ws + 6 * MB);
  bf16* qh   = (bf16*)(ws + 8 * MB);   // [8192][1024] bf16
  bf16* kh   = (bf16*)(ws + 24 * MB);
  bf16* vt   = (bf16*)(ws + 40 * MB);  // [4096][2048] transposed V
  bf16* ctx  = (bf16*)(ws + 56 * MB);  // ends at 72 MB

  float* outp  = (float*)d_out;
  float* attnp = outp + (size_t)BLc * Dc;

  cvt_all<<<2048, 256, 0, stream>>>(Wq, Wk, Wv, Wfc, wall);

  qkv_gemm<<<dim3(64, 24), 256, 0, stream>>>(q, k, v, wall, qh, kh, vt);

  attn_kernel<<<dim3(16, 16, 4), 256, 0, stream>>>(qh, kh, vt, ctx, attnp);

  fc_gemm<<<dim3(64, 8), 256, 0, stream>>>(ctx, wfcb, outp, q);
  ln_kernel<<<8192, 256, 0, stream>>>(outp, ln_g, ln_b);
}

// Round 18
// 476.715 us; speedup vs baseline: 2.5555x; 2.5555x over previous
//
#include <hip/hip_runtime.h>
#include <hip/hip_bf16.h>

typedef __bf16 bf16;
typedef __bf16 bf16x8 __attribute__((ext_vector_type(8)));
typedef __bf16 bf16x4 __attribute__((ext_vector_type(4)));
typedef __bf16 bf16x2 __attribute__((ext_vector_type(2)));
typedef float f32x4 __attribute__((ext_vector_type(4)));
typedef float f32x16 __attribute__((ext_vector_type(16)));
typedef unsigned int u32x4 __attribute__((ext_vector_type(4)));

#define MFMA_BF16(a, b, c) __builtin_amdgcn_mfma_f32_16x16x32_bf16((a), (b), (c), 0, 0, 0)
#define MFMA32(a, b, c) __builtin_amdgcn_mfma_f32_32x32x16_bf16((a), (b), (c), 0, 0, 0)

#if defined(__has_builtin)
#if __has_builtin(__builtin_amdgcn_exp2f)
#define EXP2F(x) __builtin_amdgcn_exp2f(x)
#endif
#endif
#ifndef EXP2F
#define EXP2F(x) exp2f(x)
#endif

// Problem constants
static constexpr int Bc = 4, Lc = 2048, Dc = 1024, Hc = 16, DKc = 64;
static constexpr int BLc = Bc * Lc;  // 8192
// exp(s/8) == exp2(s * log2(e)/8)
static constexpr float CEXP = 0.18033688011112042f;

__device__ inline unsigned pk2(float a, float b) {
  bf16x2 t;
  t[0] = (bf16)a;
  t[1] = (bf16)b;
  return __builtin_bit_cast(unsigned, t);
}

// ---------------- all four weight matrices f32 -> bf16, one launch ----------
__global__ __launch_bounds__(256) void cvt_all(const float* __restrict__ s0,
                                               const float* __restrict__ s1,
                                               const float* __restrict__ s2,
                                               const float* __restrict__ s3,
                                               bf16* __restrict__ dst) {
  size_t i = ((size_t)blockIdx.x * 256 + threadIdx.x) * 8;
  const float* srcs[4] = {s0, s1, s2, s3};
  const float* sp = srcs[i >> 20] + (i & 1048575);
  float4 f0 = ((const float4*)sp)[0];
  float4 f1 = ((const float4*)sp)[1];
  bf16x8 o;
  o[0] = (bf16)f0.x; o[1] = (bf16)f0.y; o[2] = (bf16)f0.z; o[3] = (bf16)f0.w;
  o[4] = (bf16)f1.x; o[5] = (bf16)f1.y; o[6] = (bf16)f1.z; o[7] = (bf16)f1.w;
  *(bf16x8*)(dst + i) = o;
}

// ---------------- merged QKV projection (unchanged from R10) -----------------
__global__ __launch_bounds__(256) void qkv_gemm(const float* __restrict__ qin,
                                                const float* __restrict__ kin,
                                                const float* __restrict__ vin,
                                                const bf16* __restrict__ Wb,
                                                bf16* __restrict__ qh,
                                                bf16* __restrict__ kh,
                                                bf16* __restrict__ vt) {
  __shared__ bf16 As[128][72];
  __shared__ bf16 Bs[128][72];
  const int t = threadIdx.x;
  const int lane = t & 63, wid = t >> 6;
  const int wr = wid >> 1, wc = wid & 1;
  const int which = blockIdx.y >> 3;
  const int m0 = blockIdx.x * 128, n0 = (blockIdx.y & 7) * 128;
  const float* A = which == 0 ? qin : which == 1 ? kin : vin;
  const bf16* Bw = Wb + ((size_t)which << 20);
  const int sub = t & 7, srow = t >> 3;

  f32x4 acc[4][4] = {};

  for (int kt = 0; kt < 1024; kt += 64) {
#pragma unroll
    for (int s = 0; s < 4; ++s) {
      int r = srow + 32 * s;
      const float4* pa = (const float4*)(A + (size_t)(m0 + r) * 1024 + kt + sub * 8);
      float4 f0 = pa[0], f1 = pa[1];
      bf16x8 o;
      o[0] = (bf16)f0.x; o[1] = (bf16)f0.y; o[2] = (bf16)f0.z; o[3] = (bf16)f0.w;
      o[4] = (bf16)f1.x; o[5] = (bf16)f1.y; o[6] = (bf16)f1.z; o[7] = (bf16)f1.w;
      *(bf16x8*)&As[r][sub * 8] = o;
    }
#pragma unroll
    for (int s = 0; s < 4; ++s) {
      int r = srow + 32 * s;
      u32x4 u = *(const u32x4*)(Bw + (size_t)(n0 + r) * 1024 + kt + sub * 8);
      *(u32x4*)&Bs[r][sub * 8] = u;
    }
    __syncthreads();
#pragma unroll
    for (int c = 0; c < 2; ++c) {
      const int ko = c * 32 + (lane >> 4) * 8;
      bf16x8 af[4], bfr[4];
#pragma unroll
      for (int m = 0; m < 4; ++m)
        af[m] = *(const bf16x8*)&As[wr * 64 + m * 16 + (lane & 15)][ko];
#pragma unroll
      for (int n = 0; n < 4; ++n)
        bfr[n] = *(const bf16x8*)&Bs[wc * 64 + n * 16 + (lane & 15)][ko];
#pragma unroll
      for (int m = 0; m < 4; ++m)
#pragma unroll
        for (int n = 0; n < 4; ++n)
          acc[m][n] = MFMA_BF16(af[m], bfr[n], acc[m][n]);
    }
    __syncthreads();
  }

  const int rbase = m0 + wr * 64 + (lane >> 4) * 4;
  const int cbase = n0 + wc * 64 + (lane & 15);
  if (which < 2) {
    bf16* C = which == 0 ? qh : kh;
#pragma unroll
    for (int m = 0; m < 4; ++m)
#pragma unroll
      for (int n = 0; n < 4; ++n)
#pragma unroll
        for (int r = 0; r < 4; ++r) {
          size_t row = (size_t)(rbase + m * 16 + r);
          size_t col = (size_t)(cbase + n * 16);
          C[row * 1024 + col] = (bf16)acc[m][n][r];
        }
  } else {
#pragma unroll
    for (int m = 0; m < 4; ++m)
#pragma unroll
      for (int n = 0; n < 4; ++n) {
        int row = rbase + m * 16;
        int col = cbase + n * 16;
        bf16x4 o;
#pragma unroll
        for (int r = 0; r < 4; ++r) o[r] = (bf16)acc[m][n][r];
        size_t dst = ((size_t)((row >> 11) << 10) + col) * 2048 + (row & 2047);
        *(bf16x4*)(vt + dst) = o;
      }
  }
}

// ---------------- fc GEMM (unchanged from R10) ----------------
__global__ __launch_bounds__(256) void fc_gemm(const bf16* __restrict__ A,
                                               const bf16* __restrict__ Bw,
                                               float* __restrict__ C,
                                               const float* __restrict__ resid) {
  __shared__ bf16 As[128][72];
  __shared__ bf16 Bs[128][72];
  const int t = threadIdx.x;
  const int lane = t & 63, wid = t >> 6;
  const int wr = wid >> 1, wc = wid & 1;
  const int m0 = blockIdx.x * 128, n0 = blockIdx.y * 128;
  const int sub = t & 7, srow = t >> 3;

  f32x4 acc[4][4] = {};

  for (int kt = 0; kt < 1024; kt += 64) {
#pragma unroll
    for (int s = 0; s < 4; ++s) {
      int r = srow + 32 * s;
      u32x4 u = *(const u32x4*)(A + (size_t)(m0 + r) * 1024 + kt + sub * 8);
      *(u32x4*)&As[r][sub * 8] = u;
    }
#pragma unroll
    for (int s = 0; s < 4; ++s) {
      int r = srow + 32 * s;
      u32x4 u = *(const u32x4*)(Bw + (size_t)(n0 + r) * 1024 + kt + sub * 8);
      *(u32x4*)&Bs[r][sub * 8] = u;
    }
    __syncthreads();
#pragma unroll
    for (int c = 0; c < 2; ++c) {
      const int ko = c * 32 + (lane >> 4) * 8;
      bf16x8 af[4], bfr[4];
#pragma unroll
      for (int m = 0; m < 4; ++m)
        af[m] = *(const bf16x8*)&As[wr * 64 + m * 16 + (lane & 15)][ko];
#pragma unroll
      for (int n = 0; n < 4; ++n)
        bfr[n] = *(const bf16x8*)&Bs[wc * 64 + n * 16 + (lane & 15)][ko];
#pragma unroll
      for (int m = 0; m < 4; ++m)
#pragma unroll
        for (int n = 0; n < 4; ++n)
          acc[m][n] = MFMA_BF16(af[m], bfr[n], acc[m][n]);
    }
    __syncthreads();
  }

  const int rbase = m0 + wr * 64 + (lane >> 4) * 4;
  const int cbase = n0 + wc * 64 + (lane & 15);
#pragma unroll
  for (int m = 0; m < 4; ++m)
#pragma unroll
    for (int n = 0; n < 4; ++n)
#pragma unroll
      for (int r = 0; r < 4; ++r) {
        size_t row = (size_t)(rbase + m * 16 + r);
        size_t col = (size_t)(cbase + n * 16);
        C[row * 1024 + col] = acc[m][n][r] + resid[row * 1024 + col];
      }
}

// ---------------- fused attention (R14 champion body, restored) ----------------
// R10 body (single-buffered phase A, 128-row phase B) at 4 blocks/CU with the
// register diet: exp inlined into pk2 (no p[16]); ctx epilogue per-element
// __shfl. Phase-B stores are PLAIN float4 stores -- R17 measured nt-stores at
// 23% HBM peak with 1.7x write amplification (L2 write-combining is load-
// bearing for this scattered 16B/row pattern).
__global__ __launch_bounds__(256, 4) void attn_kernel(const bf16* __restrict__ qh,
                                                      const bf16* __restrict__ kh,
                                                      const bf16* __restrict__ vt,
                                                      bf16* __restrict__ ctx,
                                                      float* __restrict__ attn_out) {
  __shared__ bf16 Ks[64][72];
  __shared__ bf16 Vs[64][72];  // phase A: V[dv][token]; phase B: K rows 64-127
  const int t = threadIdx.x, lane = t & 63, w = t >> 6;
  const int hi = lane >> 5, ql = lane & 31;
  const int qt = blockIdx.x, h = blockIdx.y, b = blockIdx.z;
  const size_t rowbase = (size_t)b * 2048;
  const int qrow = qt * 128 + w * 32 + ql;
  const bf16* kbase = kh + rowbase * 1024 + h * 64;
  const bf16* vbase = vt + (size_t)(b * 16 + h) * 64 * 2048;
  const int sub = t & 7, srow = t >> 3;

  bf16x8 qf[4];
  {
    const bf16* qp = qh + (rowbase + qrow) * 1024 + h * 64 + hi * 8;
#pragma unroll
    for (int c = 0; c < 4; ++c) qf[c] = *(const bf16x8*)(qp + c * 16);
  }

  f32x16 cacc[2] = {};
  float zacc = 0.f;

  // ---------- Phase A (single-buffered) ----------
  for (int kt = 0; kt < 2048; kt += 64) {
    __syncthreads();
#pragma unroll
    for (int s = 0; s < 2; ++s) {
      int r = srow + 32 * s;
      *(u32x4*)&Ks[r][sub * 8] =
          *(const u32x4*)(kbase + (size_t)(kt + r) * 1024 + sub * 8);
      *(u32x4*)&Vs[r][sub * 8] =
          *(const u32x4*)(vbase + (size_t)r * 2048 + kt + sub * 8);
    }
    __syncthreads();
#pragma unroll
    for (int sb = 0; sb < 2; ++sb) {
      f32x16 s = {};
#pragma unroll
      for (int c = 0; c < 4; ++c) {
        bf16x8 kf = *(const bf16x8*)&Ks[sb * 32 + ql][c * 16 + hi * 8];
        s = MFMA32(kf, qf[c], s);
      }
      unsigned pv[4][2];
#pragma unroll
      for (int o = 0; o < 4; ++o)
#pragma unroll
        for (int d = 0; d < 2; ++d) {
          float e0 = EXP2F(s[o * 4 + 2 * d] * CEXP);
          float e1 = EXP2F(s[o * 4 + 2 * d + 1] * CEXP);
          zacc += e0 + e1;
          pv[o][d] = pk2(e0, e1);
        }
      bf16x8 pa[2];
#pragma unroll
      for (int c = 0; c < 2; ++c) {
        u32x4 pu;
#pragma unroll
        for (int d = 0; d < 2; ++d) {
          unsigned a = pv[2 * c][d], bq = pv[2 * c + 1][d];
          unsigned as = (unsigned)__shfl_xor((int)a, 32);
          unsigned bs = (unsigned)__shfl_xor((int)bq, 32);
          pu[d] = hi ? bs : a;
          pu[2 + d] = hi ? bq : as;
        }
        pa[c] = __builtin_bit_cast(bf16x8, pu);
      }
#pragma unroll
      for (int n = 0; n < 2; ++n)
#pragma unroll
        for (int c = 0; c < 2; ++c) {
          bf16x8 vf = *(const bf16x8*)&Vs[n * 32 + ql][sb * 32 + c * 16 + hi * 8];
          cacc[n] = MFMA32(pa[c], vf, cacc[n]);
        }
    }
  }

  float z = zacc + __shfl_xor(zacc, 32);
  float rz = 1.0f / z;

  // ctx write: per-element shfl (no rzv array)
#pragma unroll
  for (int g = 0; g < 16; ++g) {
    int crow = (g & 3) + 8 * (g >> 2) + 4 * hi;
    float rv = __shfl(rz, crow);
    size_t row = rowbase + (size_t)(qt * 128 + w * 32 + crow);
    ctx[row * 1024 + h * 64 + ql] = (bf16)(cacc[0][g] * rv);
    ctx[row * 1024 + h * 64 + 32 + ql] = (bf16)(cacc[1][g] * rv);
  }

  // ---------- Phase B: attn = exp(s)/Z, 128 K-rows per barrier pair ----------
  float* abase = attn_out + ((size_t)(b * 16 + h) * 2048 + qrow) * 2048;
  for (int kt = 0; kt < 2048; kt += 128) {
    __syncthreads();  // previous 128-row chunk fully consumed
#pragma unroll
    for (int s = 0; s < 2; ++s) {
      int r = srow + 32 * s;
      *(u32x4*)&Ks[r][sub * 8] =
          *(const u32x4*)(kbase + (size_t)(kt + r) * 1024 + sub * 8);
      *(u32x4*)&Vs[r][sub * 8] =
          *(const u32x4*)(kbase + (size_t)(kt + 64 + r) * 1024 + sub * 8);
    }
    __syncthreads();
#pragma unroll
    for (int half = 0; half < 2; ++half) {
      const bf16(*Kb)[72] = half ? Vs : Ks;
      const int koff = kt + half * 64;
#pragma unroll
      for (int sb = 0; sb < 2; ++sb) {
        f32x16 s = {};
#pragma unroll
        for (int c = 0; c < 4; ++c) {
          bf16x8 kf = *(const bf16x8*)&Kb[sb * 32 + ql][c * 16 + hi * 8];
          s = MFMA32(kf, qf[c], s);
        }
#pragma unroll
        for (int o = 0; o < 4; ++o) {
          float4 v4;
          v4.x = EXP2F(s[o * 4 + 0] * CEXP) * rz;
          v4.y = EXP2F(s[o * 4 + 1] * CEXP) * rz;
          v4.z = EXP2F(s[o * 4 + 2] * CEXP) * rz;
          v4.w = EXP2F(s[o * 4 + 3] * CEXP) * rz;
          *(float4*)(abase + koff + sb * 32 + o * 8 + hi * 4) = v4;
        }
      }
    }
  }
}

// ---------------- LayerNorm (in-place on d_out rows) ----------------
__global__ __launch_bounds__(256) void ln_kernel(float* __restrict__ io,
                                                 const float* __restrict__ g,
                                                 const float* __restrict__ bta) {
  const int row = blockIdx.x, t = threadIdx.x;
  float4* rp = (float4*)(io + (size_t)row * 1024);
  float4 v = rp[t];
  float s = v.x + v.y + v.z + v.w;
  float s2 = v.x * v.x + v.y * v.y + v.z * v.z + v.w * v.w;
#pragma unroll
  for (int off = 32; off >= 1; off >>= 1) {
    s += __shfl_xor(s, off);
    s2 += __shfl_xor(s2, off);
  }
  __shared__ float ls[4], ls2[4];
  const int w = t >> 6;
  if ((t & 63) == 0) { ls[w] = s; ls2[w] = s2; }
  __syncthreads();
  s = ls[0] + ls[1] + ls[2] + ls[3];
  s2 = ls2[0] + ls2[1] + ls2[2] + ls2[3];
  float mu = s * (1.f / 1024.f);
  float var = s2 * (1.f / 1024.f) - mu * mu;
  float rs = rsqrtf(var + 1e-6f);
  float4 gv = ((const float4*)g)[t];
  float4 bv = ((const float4*)bta)[t];
  v.x = (v.x - mu) * rs * gv.x + bv.x;
  v.y = (v.y - mu) * rs * gv.y + bv.y;
  v.z = (v.z - mu) * rs * gv.z + bv.z;
  v.w = (v.w - mu) * rs * gv.w + bv.w;
  rp[t] = v;
}

extern "C" void kernel_launch(void* const* d_in, const int* in_sizes, int n_in,
                              void* d_out, int out_size, void* d_ws, size_t ws_size,
                              hipStream_t stream) {
  (void)in_sizes; (void)n_in; (void)out_size; (void)ws_size;
  const float* q    = (const float*)d_in[0];
  const float* k    = (const float*)d_in[1];
  const float* v    = (const float*)d_in[2];
  const float* Wq   = (const float*)d_in[3];
  const float* Wk   = (const float*)d_in[4];
  const float* Wv   = (const float*)d_in[5];
  const float* Wfc  = (const float*)d_in[6];
  const float* ln_g = (const float*)d_in[7];
  const float* ln_b = (const float*)d_in[8];

  char* ws = (char*)d_ws;
  const size_t MB = 1024ull * 1024ull;
  bf16* wall = (bf16*)(ws + 0 * MB);   // wq|wk|wv|wfc contiguous, 2 MB each
  bf16* wfcb = (bf16*)(ws + 6 * MB);
  bf16* qh   = (bf16*)(ws + 8 * MB);   // [8192][1024] bf16
  bf16* kh   = (bf16*)(ws + 24 * MB);
  bf16* vt   = (bf16*)(ws + 40 * MB);  // [4096][2048] transposed V
  bf16* ctx  = (bf16*)(ws + 56 * MB);  // ends at 72 MB

  float* outp  = (float*)d_out;
  float* attnp = outp + (size_t)BLc * Dc;

  cvt_all<<<2048, 256, 0, stream>>>(Wq, Wk, Wv, Wfc, wall);

  qkv_gemm<<<dim3(64, 24), 256, 0, stream>>>(q, k, v, wall, qh, kh, vt);

  attn_kernel<<<dim3(16, 16, 4), 256, 0, stream>>>(qh, kh, vt, ctx, attnp);

  fc_gemm<<<dim3(64, 8), 256, 0, stream>>>(ctx, wfcb, outp, q);
  ln_kernel<<<8192, 256, 0, stream>>>(outp, ln_g, ln_b);
}